// Round 6
// baseline (112.937 us; speedup 1.0000x reference)
//
#include <hip/hip_runtime.h>
#include <hip/hip_bf16.h>

// Problem constants
#define B_    32
#define M_    1024
#define H_    128
#define SPAN_ 1024
#define KL_   2048
#define NITER 17
#define SCALE 0.08838834764831845f

typedef __attribute__((ext_vector_type(8))) short bf16x8;
typedef __attribute__((ext_vector_type(4))) float f32x4;

// workspace: pos pre-converted to bf16, [16 tiles][64 l-rows][256 B] linear
#define WSNEED 262144ull

static __device__ __forceinline__ unsigned int cvt_pk2(float lo, float hi) {
  unsigned int r;
  asm("v_cvt_pk_bf16_f32 %0, %1, %2" : "=v"(r) : "v"(lo), "v"(hi));
  return r;
}
static __device__ __forceinline__ unsigned short f2b(float x) {
  unsigned int u = __builtin_bit_cast(unsigned int, x);
  return (unsigned short)((u + 0x7FFFu + ((u >> 16) & 1u)) >> 16);
}
static __device__ __forceinline__ float b2f(unsigned short u) {
  return __builtin_bit_cast(float, ((unsigned int)u) << 16);
}
static __device__ __forceinline__ bf16x8 ldfrag(const char* p) {
  short4 a = *(const short4*)p;
  short4 b = *(const short4*)(p + 8);
  bf16x8 r;
  r[0] = a.x; r[1] = a.y; r[2] = a.z; r[3] = a.w;
  r[4] = b.x; r[5] = b.y; r[6] = b.z; r[7] = b.w;
  return r;
}

// ======================= pos pre-conversion (tiny) =======================
// 16 blocks: tile lt = [64 l-rows][128 h] bf16, row-major l, linear (no swizzle)
__global__ void __launch_bounds__(256) convP2(const float* __restrict__ pe,
                                              char* __restrict__ out) {
  __shared__ float tile[128 * 66];
  int lt = blockIdx.x, tid = threadIdx.x;
#pragma unroll
  for (int i = 0; i < 8; ++i) {
    int idx = i * 256 + tid;
    int h = idx >> 4, c4 = idx & 15;
    float4 x = *(const float4*)(pe + (size_t)h * 1024 + lt * 64 + c4 * 4);
    tile[h * 66 + c4 * 4 + 0] = x.x; tile[h * 66 + c4 * 4 + 1] = x.y;
    tile[h * 66 + c4 * 4 + 2] = x.z; tile[h * 66 + c4 * 4 + 3] = x.w;
  }
  __syncthreads();
  char* dst = out + (size_t)lt * 16384;
#pragma unroll
  for (int j = 0; j < 4; ++j) {
    int u = tid >> 4;               // 0..15  (h-chunk of 8)
    int l = (tid & 15) + 16 * j;    // 0..63
    uint4 d;
    d.x = cvt_pk2(tile[(8 * u + 0) * 66 + l], tile[(8 * u + 1) * 66 + l]);
    d.y = cvt_pk2(tile[(8 * u + 2) * 66 + l], tile[(8 * u + 3) * 66 + l]);
    d.z = cvt_pk2(tile[(8 * u + 4) * 66 + l], tile[(8 * u + 5) * 66 + l]);
    d.w = cvt_pk2(tile[(8 * u + 6) * 66 + l], tile[(8 * u + 7) * 66 + l]);
    *(uint4*)(dst + l * 256 + 16 * u) = d;
  }
}

// ======================= main kernel =======================
// LDS (16B-aligned pitches, all frag reads = single ds_read_b128):
//   KL [64][272]  = 17408  @ 0
//   VT [128][144] = 18432  @ 17408
//   PR [64][272]  = 17408  @ 35840   (Q staging at start, then j-indexed bias ring, 128 entries)
//   PW [64][144]  = 9216   @ 53248
#define MP_A  272
#define MP_V  144
#define MP_W  144
#define L_KL  0
#define L_VT  17408
#define L_PR  35840
#define L_PW  53248
#define LDS_MAIN 62464

__global__ void __launch_bounds__(256, 2) seqattn_main(
    const float* __restrict__ q, const float* __restrict__ kkey,
    const float* __restrict__ vval, const char* __restrict__ posws,
    float* __restrict__ out) {
  extern __shared__ char smem[];
  char* KLp = smem + L_KL;
  char* VTp = smem + L_VT;
  char* PRp = smem + L_PR;
  char* PWp = smem + L_PW;

  // XCD-aware swizzle (bijective: 512 = 8*64)
  int jb = blockIdx.x;
  int o  = (jb & 7) * 64 + (jb >> 3);
  int b  = o >> 4;
  int m0 = (o & 15) * 64;

  int tid  = threadIdx.x;
  int w    = tid >> 6;
  int lane = tid & 63;
  int g    = lane >> 4;
  int c    = lane & 15;
  int r0   = tid >> 5;   // 0..7
  int c4   = tid & 31;   // 0..31
  int mrow = 16 * w + c;

  const float* qbase = q    + ((size_t)b * M_  + m0) * H_;
  const float* kbase = kkey + ((size_t)b * KL_ + m0) * H_;
  const float* vbase = vval + ((size_t)b * KL_ + m0) * H_;

  float4 kpre[8];
  float2 vpre[16];

#define MLOADK(tt) do {                                                       \
    const float* kb_ = kbase + (size_t)(64 * (tt)) * H_;                      \
    _Pragma("unroll")                                                         \
    for (int p = 0; p < 8; ++p)                                               \
      kpre[p] = *(const float4*)(kb_ + (p * 8 + r0) * H_ + c4 * 4);           \
  } while (0)

#define MWRITEK() do {                                                        \
    _Pragma("unroll")                                                         \
    for (int p = 0; p < 8; ++p) {                                             \
      float4 v_ = kpre[p];                                                    \
      uint2 d_; d_.x = cvt_pk2(v_.x, v_.y); d_.y = cvt_pk2(v_.z, v_.w);       \
      *(uint2*)(KLp + (p * 8 + r0) * MP_A + c4 * 8) = d_;                     \
    }                                                                         \
  } while (0)

#define MLOADV(tt) do {                                                       \
    const float* vb_ = vbase + (size_t)(64 * (tt)) * H_;                      \
    _Pragma("unroll")                                                         \
    for (int qq = 0; qq < 4; ++qq) {                                          \
      int kq_ = 4 * (4 * w + qq);                                             \
      _Pragma("unroll")                                                       \
      for (int r = 0; r < 4; ++r)                                             \
        vpre[qq * 4 + r] = *(const float2*)(vb_ + (kq_ + r) * H_ + 2 * lane); \
    }                                                                         \
  } while (0)

#define MWRITEV() do {                                                        \
    _Pragma("unroll")                                                         \
    for (int qq = 0; qq < 4; ++qq) {                                          \
      int kq_ = 4 * w + qq;                                                   \
      uint2 lo_, hi_;                                                         \
      lo_.x = cvt_pk2(vpre[qq * 4 + 0].x, vpre[qq * 4 + 1].x);                \
      lo_.y = cvt_pk2(vpre[qq * 4 + 2].x, vpre[qq * 4 + 3].x);                \
      hi_.x = cvt_pk2(vpre[qq * 4 + 0].y, vpre[qq * 4 + 1].y);                \
      hi_.y = cvt_pk2(vpre[qq * 4 + 2].y, vpre[qq * 4 + 3].y);                \
      *(uint2*)(VTp + (2 * lane + 0) * MP_V + 8 * kq_) = lo_;                 \
      *(uint2*)(VTp + (2 * lane + 1) * MP_V + 8 * kq_) = hi_;                 \
    }                                                                         \
  } while (0)

  // ---- prologue: Q f32 -> bf16 (pre-scaled) into PR; issue K/V tile 0 ----
  {
    float4 qpre[8];
#pragma unroll
    for (int p = 0; p < 8; ++p)
      qpre[p] = *(const float4*)(qbase + (p * 8 + r0) * H_ + c4 * 4);
    MLOADK(0); MLOADV(0);
#pragma unroll
    for (int p = 0; p < 8; ++p) {
      float4 v_ = qpre[p];
      uint2 d_;
      d_.x = cvt_pk2(v_.x * SCALE, v_.y * SCALE);
      d_.y = cvt_pk2(v_.z * SCALE, v_.w * SCALE);
      *(uint2*)(PRp + (p * 8 + r0) * MP_A + c4 * 8) = d_;
    }
  }
  __syncthreads();

  bf16x8 qf[4];
#pragma unroll
  for (int hs = 0; hs < 4; ++hs)
    qf[hs] = *(const bf16x8*)(PRp + mrow * MP_A + hs * 64 + g * 16);
  __syncthreads();   // PR free for ring use

  f32x4 O[8];
#pragma unroll
  for (int i = 0; i < 8; ++i) { O[i][0] = 0.f; O[i][1] = 0.f; O[i][2] = 0.f; O[i][3] = 0.f; }
  float mrun = -1e30f, lrun = 0.f;
  char* prRow = PRp + mrow * MP_A;
  char* pwRow = PWp + mrow * MP_W;

#pragma unroll 1
  for (int t = 0; t < NITER; ++t) {
    // ---- commit staged K/V tile t to LDS (regs loaded during iter t-1) ----
    MWRITEK();
    MWRITEV();

    // ---- bias chunk t: pos frags DIRECT from L2 ws; ring is j-indexed ----
    if (t < 16) {
      const char* pt = posws + (size_t)t * 16384;
      int xbase = (64 * t + mrow) & 127;
#pragma unroll
      for (int lt = 0; lt < 4; ++lt) {
        f32x4 pb = {0.f, 0.f, 0.f, 0.f};
#pragma unroll
        for (int hs = 0; hs < 4; ++hs) {
          bf16x8 pf = *(const bf16x8*)(pt + (16 * lt + c) * 256 + hs * 64 + g * 16);
          pb = __builtin_amdgcn_mfma_f32_16x16x32_bf16(pf, qf[hs], pb, 0, 0, 0);
        }
        int xb = xbase + 16 * lt + 4 * g;
#pragma unroll
        for (int rr = 0; rr < 4; ++rr) {
          int x = xb + rr;
          x = (x >= 128) ? x - 128 : x;
          *(unsigned short*)(prRow + x * 2) = f2b(pb[rr]);
        }
      }
    }
    __syncthreads();  // barrier A: KL/VT tile t visible to all waves

    // ---- issue global f32 loads for tile t+1 (covered by S+softmax+PV) ----
    if (t < 16) { MLOADK(t + 1); MLOADV(t + 1); }
    __builtin_amdgcn_sched_barrier(0);  // pin loads here (no sinking)

    // ---- S^T = K Q^T ----
    f32x4 s[4];
    __builtin_amdgcn_s_setprio(1);
#pragma unroll
    for (int nt = 0; nt < 4; ++nt) {
      f32x4 acc = {0.f, 0.f, 0.f, 0.f};
#pragma unroll
      for (int hs = 0; hs < 4; ++hs) {
        bf16x8 kf = *(const bf16x8*)(KLp + (16 * nt + c) * MP_A + hs * 64 + g * 16);
        acc = __builtin_amdgcn_mfma_f32_16x16x32_bf16(kf, qf[hs], acc, 0, 0, 0);
      }
      s[nt] = acc;
    }
    __builtin_amdgcn_s_setprio(0);

    // ---- bias add (j-indexed ring, aligned b64 reads) + band mask ----
#pragma unroll
    for (int nt = 0; nt < 4; ++nt) {
      int x4 = (64 * t + 16 * nt + 4 * g) & 127;   // multiple of 4
      ushort4 bv = *(const ushort4*)(prRow + x4 * 2);
      int lbase = 64 * t + 16 * nt + 4 * g - mrow;
      const unsigned short* bp = (const unsigned short*)&bv;
#pragma unroll
      for (int rr = 0; rr < 4; ++rr) {
        float sv = s[nt][rr] + b2f(bp[rr]);
        s[nt][rr] = ((unsigned)(lbase + rr) < 1024u) ? sv : -1e30f;
      }
    }

    // ---- online softmax (per-lane row, defer-max) ----
    float pmax = -1e30f;
#pragma unroll
    for (int nt = 0; nt < 4; ++nt)
#pragma unroll
      for (int rr = 0; rr < 4; ++rr) pmax = fmaxf(pmax, s[nt][rr]);
    pmax = fmaxf(pmax, __shfl_xor(pmax, 16, 64));
    pmax = fmaxf(pmax, __shfl_xor(pmax, 32, 64));
    if (__any(pmax > mrun + 8.0f)) {
      float mn = fmaxf(mrun, pmax);
      float corr = __expf(mrun - mn);
      mrun = mn;
      lrun *= corr;
#pragma unroll
      for (int i = 0; i < 8; ++i) {
        O[i][0] *= corr; O[i][1] *= corr; O[i][2] *= corr; O[i][3] *= corr;
      }
    }
    float rsum = 0.f;
#pragma unroll
    for (int nt = 0; nt < 4; ++nt) {
      float p0 = __expf(s[nt][0] - mrun);
      float p1 = __expf(s[nt][1] - mrun);
      float p2 = __expf(s[nt][2] - mrun);
      float p3 = __expf(s[nt][3] - mrun);
      rsum += (p0 + p1) + (p2 + p3);
      uint2 d_;
      d_.x = cvt_pk2(p0, p1);
      d_.y = cvt_pk2(p2, p3);
      *(uint2*)(pwRow + (16 * nt + 4 * g) * 2) = d_;
    }
    rsum += __shfl_xor(rsum, 16, 64);
    rsum += __shfl_xor(rsum, 32, 64);
    lrun += rsum;

    // ---- O^T += V^T P^T ----
    __builtin_amdgcn_s_setprio(1);
#pragma unroll
    for (int ks = 0; ks < 2; ++ks) {
      bf16x8 pfrag = *(const bf16x8*)(pwRow + ks * 64 + g * 16);
#pragma unroll
      for (int nt = 0; nt < 8; ++nt) {
        bf16x8 vfr = *(const bf16x8*)(VTp + (16 * nt + c) * MP_V + ks * 64 + g * 16);
        O[nt] = __builtin_amdgcn_mfma_f32_16x16x32_bf16(vfr, pfrag, O[nt], 0, 0, 0);
      }
    }
    __builtin_amdgcn_s_setprio(0);
    __syncthreads();  // barrier B: all waves done reading KL/VT tile t
  }

  // ---- normalize + store ----
  float inv = 1.0f / lrun;
  float* ob = out + ((size_t)b * M_ + m0 + mrow) * H_;
#pragma unroll
  for (int nt = 0; nt < 8; ++nt) {
    float4 vv;
    vv.x = O[nt][0] * inv; vv.y = O[nt][1] * inv;
    vv.z = O[nt][2] * inv; vv.w = O[nt][3] * inv;
    *(float4*)(ob + 16 * nt + 4 * g) = vv;
  }
}

// ======================= fallback (round-2 kernel, no ws) =======================
#define PITCH_A  264
#define PITCH_VT 136
#define PITCH_PR 264
#define PITCH_PW 136
#define OFF_K  0
#define OFF_VT 16896
#define OFF_PT 34304
#define OFF_PR 51200
#define OFF_PW 68096
#define LDS_FB 76800

__global__ void __launch_bounds__(256, 2) seqattn_fb(
    const float* __restrict__ q, const float* __restrict__ kkey,
    const float* __restrict__ vval, const float* __restrict__ pe,
    float* __restrict__ out) {
  extern __shared__ char smem[];
  char* KL = smem + OFF_K;
  char* VT = smem + OFF_VT;
  char* PT = smem + OFF_PT;
  char* PR = smem + OFF_PR;
  char* PW = smem + OFF_PW;

  int jb = blockIdx.x;
  int o  = (jb & 7) * 64 + (jb >> 3);
  int b  = o >> 4;
  int m0 = (o & 15) * 64;

  int tid  = threadIdx.x;
  int w    = tid >> 6;
  int lane = tid & 63;
  int g    = lane >> 4;
  int c    = lane & 15;
  int r0   = tid >> 5;
  int c4   = tid & 31;

  const float* qbase = q    + ((size_t)b * M_  + m0) * H_;
  const float* kbase = kkey + ((size_t)b * KL_ + m0) * H_;
  const float* vbase = vval + ((size_t)b * KL_ + m0) * H_;

  float4 kpre[8];
  float  vpre[32];
  float  ppre[32];

#define LOADK(tt) do {                                                        \
    const float* kb_ = kbase + (size_t)(64 * (tt)) * H_;                      \
    _Pragma("unroll")                                                         \
    for (int p = 0; p < 8; ++p)                                               \
      kpre[p] = *(const float4*)(kb_ + (p * 8 + r0) * H_ + c4 * 4);           \
  } while (0)
#define WRITEK() do {                                                         \
    _Pragma("unroll")                                                         \
    for (int p = 0; p < 8; ++p) {                                             \
      float4 v_ = kpre[p];                                                    \
      uint2 d_; d_.x = cvt_pk2(v_.x, v_.y); d_.y = cvt_pk2(v_.z, v_.w);       \
      *(uint2*)(KL + (p * 8 + r0) * PITCH_A + c4 * 8) = d_;                   \
    }                                                                         \
  } while (0)
#define LOADV(tt) do {                                                        \
    const float* vb_ = vbase + (size_t)(64 * (tt)) * H_;                      \
    _Pragma("unroll")                                                         \
    for (int qq = 0; qq < 4; ++qq) {                                          \
      int kq_ = 4 * (4 * w + qq);                                             \
      _Pragma("unroll")                                                       \
      for (int r = 0; r < 4; ++r) {                                           \
        vpre[qq * 8 + r * 2 + 0] = vb_[(kq_ + r) * H_ + lane];                \
        vpre[qq * 8 + r * 2 + 1] = vb_[(kq_ + r) * H_ + lane + 64];           \
      }                                                                       \
    }                                                                         \
  } while (0)
#define WRITEV() do {                                                         \
    _Pragma("unroll")                                                         \
    for (int qq = 0; qq < 4; ++qq) {                                          \
      int kq_ = 4 * w + qq;                                                   \
      uint2 lo_, hi_;                                                         \
      lo_.x = cvt_pk2(vpre[qq * 8 + 0], vpre[qq * 8 + 2]);                    \
      lo_.y = cvt_pk2(vpre[qq * 8 + 4], vpre[qq * 8 + 6]);                    \
      hi_.x = cvt_pk2(vpre[qq * 8 + 1], vpre[qq * 8 + 3]);                    \
      hi_.y = cvt_pk2(vpre[qq * 8 + 5], vpre[qq * 8 + 7]);                    \
      *(uint2*)(VT + lane * PITCH_VT + 8 * kq_) = lo_;                        \
      *(uint2*)(VT + (lane + 64) * PITCH_VT + 8 * kq_) = hi_;                 \
    }                                                                         \
  } while (0)
#define LOADP(tt) do {                                                        \
    const float* pb_ = pe + 64 * (tt);                                        \
    _Pragma("unroll")                                                         \
    for (int qq = 0; qq < 8; ++qq) {                                          \
      int h_ = 4 * (8 * w + qq);                                              \
      _Pragma("unroll")                                                       \
      for (int r = 0; r < 4; ++r)                                             \
        ppre[qq * 4 + r] = pb_[(h_ + r) * SPAN_ + lane];                      \
    }                                                                         \
  } while (0)
#define WRITEP() do {                                                         \
    _Pragma("unroll")                                                         \
    for (int qq = 0; qq < 8; ++qq) {                                          \
      uint2 d_;                                                               \
      d_.x = cvt_pk2(ppre[qq * 4 + 0], ppre[qq * 4 + 1]);                     \
      d_.y = cvt_pk2(ppre[qq * 4 + 2], ppre[qq * 4 + 3]);                     \
      *(uint2*)(PT + lane * PITCH_A + 8 * (8 * w + qq)) = d_;                 \
    }                                                                         \
  } while (0)

  {
    float4 qpre[8];
#pragma unroll
    for (int p = 0; p < 8; ++p)
      qpre[p] = *(const float4*)(qbase + (p * 8 + r0) * H_ + c4 * 4);
    LOADK(0); LOADV(0); LOADP(0);
#pragma unroll
    for (int p = 0; p < 8; ++p) {
      float4 v_ = qpre[p];
      uint2 d_;
      d_.x = cvt_pk2(v_.x * SCALE, v_.y * SCALE);
      d_.y = cvt_pk2(v_.z * SCALE, v_.w * SCALE);
      *(uint2*)(PR + (p * 8 + r0) * PITCH_PR + c4 * 8) = d_;
    }
    WRITEK(); WRITEV(); WRITEP();
    LOADK(1); LOADV(1); LOADP(1);
  }
  __syncthreads();

  bf16x8 qf[4];
#pragma unroll
  for (int hs = 0; hs < 4; ++hs)
    qf[hs] = ldfrag(PR + (w * 16 + c) * PITCH_PR + hs * 64 + g * 16);

  f32x4 O[8];
#pragma unroll
  for (int i = 0; i < 8; ++i) { O[i][0] = 0.f; O[i][1] = 0.f; O[i][2] = 0.f; O[i][3] = 0.f; }
  float mrun = -1e30f, lrun = 0.f;
  const int mrow = 16 * w + c;
  char* prRow = PR + mrow * PITCH_PR;
  char* pwRow = PW + mrow * PITCH_PW;

#pragma unroll 1
  for (int t = 0; t < NITER; ++t) {
    if (t < 16) {
#pragma unroll
      for (int lt = 0; lt < 4; ++lt) {
        f32x4 pb = {0.f, 0.f, 0.f, 0.f};
#pragma unroll
        for (int hs = 0; hs < 4; ++hs)
          pb = __builtin_amdgcn_mfma_f32_16x16x32_bf16(
              ldfrag(PT + (16 * lt + c) * PITCH_A + hs * 64 + g * 16), qf[hs], pb, 0, 0, 0);
#pragma unroll
        for (int rr = 0; rr < 4; ++rr) {
          int x = (64 * t + 16 * lt + 4 * g + rr + mrow) & 127;
          *(unsigned short*)(prRow + x * 2) = f2b(pb[rr]);
        }
      }
    }
    f32x4 s[4];
#pragma unroll
    for (int nt = 0; nt < 4; ++nt) {
      f32x4 acc = {0.f, 0.f, 0.f, 0.f};
#pragma unroll
      for (int hs = 0; hs < 4; ++hs)
        acc = __builtin_amdgcn_mfma_f32_16x16x32_bf16(
            ldfrag(KL + (16 * nt + c) * PITCH_A + hs * 64 + g * 16), qf[hs], acc, 0, 0, 0);
      s[nt] = acc;
    }
#pragma unroll
    for (int nt = 0; nt < 4; ++nt) {
      int x = (64 * t + 16 * nt + 4 * g) & 127;
      ushort4 bv = *(const ushort4*)(prRow + x * 2);
      int lbase = 64 * t + 16 * nt + 4 * g - mrow;
      const unsigned short* bp = (const unsigned short*)&bv;
#pragma unroll
      for (int rr = 0; rr < 4; ++rr) {
        float sv = s[nt][rr] + b2f(bp[rr]);
        s[nt][rr] = ((unsigned)(lbase + rr) < 1024u) ? sv : -1e30f;
      }
    }
    float pmax = -1e30f;
#pragma unroll
    for (int nt = 0; nt < 4; ++nt)
#pragma unroll
      for (int rr = 0; rr < 4; ++rr) pmax = fmaxf(pmax, s[nt][rr]);
    pmax = fmaxf(pmax, __shfl_xor(pmax, 16, 64));
    pmax = fmaxf(pmax, __shfl_xor(pmax, 32, 64));
    if (__any(pmax > mrun + 8.0f)) {
      float mn = fmaxf(mrun, pmax);
      float corr = __expf(mrun - mn);
      mrun = mn;
      lrun *= corr;
#pragma unroll
      for (int i = 0; i < 8; ++i) {
        O[i][0] *= corr; O[i][1] *= corr; O[i][2] *= corr; O[i][3] *= corr;
      }
    }
    float rsum = 0.f;
#pragma unroll
    for (int nt = 0; nt < 4; ++nt) {
      float p0 = __expf(s[nt][0] - mrun);
      float p1 = __expf(s[nt][1] - mrun);
      float p2 = __expf(s[nt][2] - mrun);
      float p3 = __expf(s[nt][3] - mrun);
      rsum += (p0 + p1) + (p2 + p3);
      uint2 d_;
      d_.x = cvt_pk2(p0, p1);
      d_.y = cvt_pk2(p2, p3);
      *(uint2*)(pwRow + (16 * nt + 4 * g) * 2) = d_;
    }
    rsum += __shfl_xor(rsum, 16, 64);
    rsum += __shfl_xor(rsum, 32, 64);
    lrun += rsum;
#pragma unroll
    for (int ks = 0; ks < 2; ++ks) {
      bf16x8 pfrag = ldfrag(pwRow + ks * 64 + g * 16);
#pragma unroll
      for (int nt = 0; nt < 8; ++nt)
        O[nt] = __builtin_amdgcn_mfma_f32_16x16x32_bf16(
            ldfrag(VT + (16 * nt + c) * PITCH_VT + ks * 64 + g * 16), pfrag, O[nt], 0, 0, 0);
    }
    __syncthreads();
    if (t < 16) {
      WRITEK(); WRITEV();
      if (t < 15) {
        WRITEP();
        LOADK(t + 2); LOADV(t + 2);
        if (t + 2 < 16) LOADP(t + 2);
      }
    }
    __syncthreads();
  }

  float inv = 1.0f / lrun;
  float* ob = out + ((size_t)b * M_ + m0 + mrow) * H_;
#pragma unroll
  for (int nt = 0; nt < 8; ++nt) {
    float4 vv;
    vv.x = O[nt][0] * inv; vv.y = O[nt][1] * inv;
    vv.z = O[nt][2] * inv; vv.w = O[nt][3] * inv;
    *(float4*)(ob + 16 * nt + 4 * g) = vv;
  }
}
#undef LOADK
#undef WRITEK
#undef LOADV
#undef WRITEV
#undef LOADP
#undef WRITEP

extern "C" void kernel_launch(void* const* d_in, const int* in_sizes, int n_in,
                              void* d_out, int out_size, void* d_ws, size_t ws_size,
                              hipStream_t stream) {
  const float* q  = (const float*)d_in[0];
  const float* k  = (const float*)d_in[1];
  const float* v  = (const float*)d_in[2];
  const float* pe = (const float*)d_in[3];
  float* out = (float*)d_out;

  if (ws_size >= WSNEED) {
    char* ws = (char*)d_ws;
    convP2<<<dim3(16), dim3(256), 0, stream>>>(pe, ws);
    seqattn_main<<<dim3(512), dim3(256), LDS_MAIN, stream>>>(q, k, v, ws, out);
  } else {
    (void)hipFuncSetAttribute(reinterpret_cast<const void*>(seqattn_fb),
                              hipFuncAttributeMaxDynamicSharedMemorySize, LDS_FB);
    seqattn_fb<<<dim3(512), dim3(256), LDS_FB, stream>>>(q, k, v, pe, out);
  }
}

// Round 7
// 105.424 us; speedup vs baseline: 1.0713x; 1.0713x over previous
//
#include <hip/hip_runtime.h>
#include <hip/hip_bf16.h>

// Problem constants
#define B_    32
#define M_    1024
#define H_    128
#define SPAN_ 1024
#define KL_   2048
#define NITER 17
#define SCALE 0.08838834764831845f

typedef __attribute__((ext_vector_type(8))) short bf16x8;
typedef __attribute__((ext_vector_type(4))) float f32x4;

// workspace: pos bf16, 16 tiles of [64 l-rows][128 h] = 16 KB each, linear
#define WSNEED 262144ull

static __device__ __forceinline__ unsigned int cvt_pk2(float lo, float hi) {
  unsigned int r;
  asm("v_cvt_pk_bf16_f32 %0, %1, %2" : "=v"(r) : "v"(lo), "v"(hi));
  return r;
}
static __device__ __forceinline__ unsigned short f2b(float x) {
  unsigned int u = __builtin_bit_cast(unsigned int, x);
  return (unsigned short)((u + 0x7FFFu + ((u >> 16) & 1u)) >> 16);
}
static __device__ __forceinline__ float b2f(unsigned short u) {
  return __builtin_bit_cast(float, ((unsigned int)u) << 16);
}
static __device__ __forceinline__ bf16x8 ldfrag(const char* p) {  // 8B-aligned
  short4 a = *(const short4*)p;
  short4 b = *(const short4*)(p + 8);
  bf16x8 r;
  r[0] = a.x; r[1] = a.y; r[2] = a.z; r[3] = a.w;
  r[4] = b.x; r[5] = b.y; r[6] = b.z; r[7] = b.w;
  return r;
}

// ======================= pos pre-conversion (tiny) =======================
__global__ void __launch_bounds__(256) convP2(const float* __restrict__ pe,
                                              char* __restrict__ out) {
  __shared__ float tile[128 * 66];
  int lt = blockIdx.x, tid = threadIdx.x;
#pragma unroll
  for (int i = 0; i < 8; ++i) {
    int idx = i * 256 + tid;
    int h = idx >> 4, c4 = idx & 15;
    float4 x = *(const float4*)(pe + (size_t)h * 1024 + lt * 64 + c4 * 4);
    tile[h * 66 + c4 * 4 + 0] = x.x; tile[h * 66 + c4 * 4 + 1] = x.y;
    tile[h * 66 + c4 * 4 + 2] = x.z; tile[h * 66 + c4 * 4 + 3] = x.w;
  }
  __syncthreads();
  char* dst = out + (size_t)lt * 16384;
#pragma unroll
  for (int j = 0; j < 4; ++j) {
    int u = tid >> 4;               // 0..15  (h-chunk of 8)
    int l = (tid & 15) + 16 * j;    // 0..63
    uint4 d;
    d.x = cvt_pk2(tile[(8 * u + 0) * 66 + l], tile[(8 * u + 1) * 66 + l]);
    d.y = cvt_pk2(tile[(8 * u + 2) * 66 + l], tile[(8 * u + 3) * 66 + l]);
    d.z = cvt_pk2(tile[(8 * u + 4) * 66 + l], tile[(8 * u + 5) * 66 + l]);
    d.w = cvt_pk2(tile[(8 * u + 6) * 66 + l], tile[(8 * u + 7) * 66 + l]);
    *(uint4*)(dst + l * 256 + 16 * u) = d;
  }
}

// ======================= main kernel =======================
// LDS: pow2 pitches + XOR unit swizzle (u ^= row&7) -> all frag reads b128 @ floor
//   KL [64][256]  = 16384 @ 0
//   VT [128][128] = 16384 @ 16384
//   PT [64][256]  = 16384 @ 32768
//   PR [64][264]  = 16896 @ 49152   (Q staging linear; then j-indexed bias ring)
//   PW [64][128]  = 8192  @ 66048
#define L_KL  0
#define L_VT  16384
#define L_PT  32768
#define L_PR  49152
#define L_PW  66048
#define MP_R  264
#define LDS_MAIN 74240

__global__ void __launch_bounds__(256, 2) seqattn_main(
    const float* __restrict__ q, const float* __restrict__ kkey,
    const float* __restrict__ vval, const char* __restrict__ posws,
    float* __restrict__ out) {
  extern __shared__ char smem[];
  char* KLp = smem + L_KL;
  char* VTp = smem + L_VT;
  char* PTp = smem + L_PT;
  char* PRp = smem + L_PR;
  char* PWp = smem + L_PW;

  // XCD-aware swizzle (bijective: 512 = 8*64)
  int jb = blockIdx.x;
  int o  = (jb & 7) * 64 + (jb >> 3);
  int b  = o >> 4;
  int m0 = (o & 15) * 64;

  int tid  = threadIdx.x;
  int w    = tid >> 6;
  int lane = tid & 63;
  int g    = lane >> 4;
  int c    = lane & 15;
  int r0   = tid >> 5;   // 0..7
  int c4   = tid & 31;   // 0..31
  int mrow = 16 * w + c;
  int sx   = c & 7;

  int foffA[4];
#pragma unroll
  for (int hs = 0; hs < 4; ++hs) foffA[hs] = 16 * (((hs << 2) | g) ^ sx);

  const float* qbase = q    + ((size_t)b * M_  + m0) * H_;
  const float* kbase = kkey + ((size_t)b * KL_ + m0) * H_;
  const float* vbase = vval + ((size_t)b * KL_ + m0) * H_;

  float4 kpre[8];
  float2 vpre[16];
  uint4  ppre[4];

#define MLOADK(tt) do {                                                       \
    const float* kb_ = kbase + (size_t)(64 * (tt)) * H_;                      \
    _Pragma("unroll")                                                         \
    for (int p = 0; p < 8; ++p)                                               \
      kpre[p] = *(const float4*)(kb_ + (p * 8 + r0) * H_ + c4 * 4);           \
  } while (0)

#define MWRITEK() do {                                                        \
    _Pragma("unroll")                                                         \
    for (int p = 0; p < 8; ++p) {                                             \
      float4 v_ = kpre[p];                                                    \
      uint2 d_; d_.x = cvt_pk2(v_.x, v_.y); d_.y = cvt_pk2(v_.z, v_.w);       \
      *(uint2*)(KLp + (p * 8 + r0) * 256 + 16 * ((c4 >> 1) ^ r0)              \
                + 8 * (c4 & 1)) = d_;                                         \
    }                                                                         \
  } while (0)

#define MLOADV(tt) do {                                                       \
    const float* vb_ = vbase + (size_t)(64 * (tt)) * H_;                      \
    _Pragma("unroll")                                                         \
    for (int qq = 0; qq < 4; ++qq) {                                          \
      int kq_ = 4 * (4 * w + qq);                                             \
      _Pragma("unroll")                                                       \
      for (int r = 0; r < 4; ++r)                                             \
        vpre[qq * 4 + r] = *(const float2*)(vb_ + (kq_ + r) * H_ + 2 * lane); \
    }                                                                         \
  } while (0)

#define MWRITEV() do {                                                        \
    int row0_ = 2 * lane, row1_ = 2 * lane + 1;                               \
    uint4 a0_, a1_, b0_, b1_;                                                 \
    a0_.x = cvt_pk2(vpre[0].x,  vpre[1].x);                                   \
    a0_.y = cvt_pk2(vpre[2].x,  vpre[3].x);                                   \
    a0_.z = cvt_pk2(vpre[4].x,  vpre[5].x);                                   \
    a0_.w = cvt_pk2(vpre[6].x,  vpre[7].x);                                   \
    a1_.x = cvt_pk2(vpre[8].x,  vpre[9].x);                                   \
    a1_.y = cvt_pk2(vpre[10].x, vpre[11].x);                                  \
    a1_.z = cvt_pk2(vpre[12].x, vpre[13].x);                                  \
    a1_.w = cvt_pk2(vpre[14].x, vpre[15].x);                                  \
    b0_.x = cvt_pk2(vpre[0].y,  vpre[1].y);                                   \
    b0_.y = cvt_pk2(vpre[2].y,  vpre[3].y);                                   \
    b0_.z = cvt_pk2(vpre[4].y,  vpre[5].y);                                   \
    b0_.w = cvt_pk2(vpre[6].y,  vpre[7].y);                                   \
    b1_.x = cvt_pk2(vpre[8].y,  vpre[9].y);                                   \
    b1_.y = cvt_pk2(vpre[10].y, vpre[11].y);                                  \
    b1_.z = cvt_pk2(vpre[12].y, vpre[13].y);                                  \
    b1_.w = cvt_pk2(vpre[14].y, vpre[15].y);                                  \
    *(uint4*)(VTp + row0_ * 128 + 16 * ((2 * w) ^ (row0_ & 7)))     = a0_;    \
    *(uint4*)(VTp + row0_ * 128 + 16 * ((2 * w + 1) ^ (row0_ & 7))) = a1_;    \
    *(uint4*)(VTp + row1_ * 128 + 16 * ((2 * w) ^ (row1_ & 7)))     = b0_;    \
    *(uint4*)(VTp + row1_ * 128 + 16 * ((2 * w + 1) ^ (row1_ & 7))) = b1_;    \
  } while (0)

#define MLOADP(tt) do {                                                       \
    const char* pt_ = posws + (size_t)(tt) * 16384;                           \
    _Pragma("unroll")                                                         \
    for (int i = 0; i < 4; ++i)                                               \
      ppre[i] = *(const uint4*)(pt_ + (i * 256 + tid) * 16);                  \
  } while (0)

#define MWRITEP() do {                                                        \
    _Pragma("unroll")                                                         \
    for (int i = 0; i < 4; ++i) {                                             \
      int idx_ = i * 256 + tid;                                               \
      int pr_ = idx_ >> 4, pu_ = idx_ & 15;                                   \
      *(uint4*)(PTp + pr_ * 256 + 16 * (pu_ ^ (pr_ & 7))) = ppre[i];          \
    }                                                                         \
  } while (0)

  // ---- prologue: Q -> PR (linear, pre-scaled); load tile-0 regs ----
  {
    float4 qpre[8];
#pragma unroll
    for (int p = 0; p < 8; ++p)
      qpre[p] = *(const float4*)(qbase + (p * 8 + r0) * H_ + c4 * 4);
    MLOADK(0); MLOADV(0); MLOADP(0);
#pragma unroll
    for (int p = 0; p < 8; ++p) {
      float4 v_ = qpre[p];
      uint2 d_;
      d_.x = cvt_pk2(v_.x * SCALE, v_.y * SCALE);
      d_.y = cvt_pk2(v_.z * SCALE, v_.w * SCALE);
      *(uint2*)(PRp + (p * 8 + r0) * MP_R + c4 * 8) = d_;
    }
  }
  __syncthreads();

  bf16x8 qf[4];
#pragma unroll
  for (int hs = 0; hs < 4; ++hs)
    qf[hs] = ldfrag(PRp + mrow * MP_R + hs * 64 + g * 16);
  __syncthreads();   // PR free for ring use

  f32x4 O[8];
#pragma unroll
  for (int i = 0; i < 8; ++i) { O[i][0] = 0.f; O[i][1] = 0.f; O[i][2] = 0.f; O[i][3] = 0.f; }
  float mrun = -1e30f, lrun = 0.f;
  char* prRow = PRp + mrow * MP_R;
  char* pwRow = PWp + mrow * 128;

#pragma unroll 1
  for (int t = 0; t < NITER; ++t) {
    // ---- commit staged tile t (regs loaded during iter t-1) ----
    MWRITEK();
    MWRITEV();
    if (t < 16) MWRITEP();
    __syncthreads();  // barrier A: tiles visible

    // ---- issue prefetch t+1 unconditionally (clamped) + pin placement ----
    {
      int tn = (t < 16) ? t + 1 : 0;
      int tp = (t < 15) ? t + 1 : 0;
      MLOADK(tn); MLOADV(tn); MLOADP(tp);
    }
    __builtin_amdgcn_sched_barrier(0);

    // ---- bias chunk t: ring[j&127] = q[mrow] . pos[:, j-mrow] ----
    if (t < 16) {
      int xbase = (64 * t + mrow) & 127;
      __builtin_amdgcn_s_setprio(1);
#pragma unroll
      for (int lt = 0; lt < 4; ++lt) {
        f32x4 pb = {0.f, 0.f, 0.f, 0.f};
#pragma unroll
        for (int hs = 0; hs < 4; ++hs) {
          bf16x8 pf = *(const bf16x8*)(PTp + (16 * lt + c) * 256 + foffA[hs]);
          pb = __builtin_amdgcn_mfma_f32_16x16x32_bf16(pf, qf[hs], pb, 0, 0, 0);
        }
        int xb = xbase + 16 * lt + 4 * g;
#pragma unroll
        for (int rr = 0; rr < 4; ++rr) {
          int x = xb + rr;
          x = (x >= 128) ? x - 128 : x;
          *(unsigned short*)(prRow + x * 2) = f2b(pb[rr]);
        }
      }
      __builtin_amdgcn_s_setprio(0);
    }

    // ---- S^T = K Q^T ----
    f32x4 s[4];
    __builtin_amdgcn_s_setprio(1);
#pragma unroll
    for (int nt = 0; nt < 4; ++nt) {
      f32x4 acc = {0.f, 0.f, 0.f, 0.f};
#pragma unroll
      for (int hs = 0; hs < 4; ++hs) {
        bf16x8 kf = *(const bf16x8*)(KLp + (16 * nt + c) * 256 + foffA[hs]);
        acc = __builtin_amdgcn_mfma_f32_16x16x32_bf16(kf, qf[hs], acc, 0, 0, 0);
      }
      s[nt] = acc;
    }
    __builtin_amdgcn_s_setprio(0);

    // ---- bias add (j-indexed ring, 8B reads) + band mask ----
#pragma unroll
    for (int nt = 0; nt < 4; ++nt) {
      int x4 = (64 * t + 16 * nt + 4 * g) & 127;
      ushort4 bv = *(const ushort4*)(prRow + x4 * 2);
      int lbase = 64 * t + 16 * nt + 4 * g - mrow;
      const unsigned short* bp = (const unsigned short*)&bv;
#pragma unroll
      for (int rr = 0; rr < 4; ++rr) {
        float sv = s[nt][rr] + b2f(bp[rr]);
        s[nt][rr] = ((unsigned)(lbase + rr) < 1024u) ? sv : -1e30f;
      }
    }

    // ---- online softmax (per-lane row, defer-max) ----
    float pmax = -1e30f;
#pragma unroll
    for (int nt = 0; nt < 4; ++nt)
#pragma unroll
      for (int rr = 0; rr < 4; ++rr) pmax = fmaxf(pmax, s[nt][rr]);
    pmax = fmaxf(pmax, __shfl_xor(pmax, 16, 64));
    pmax = fmaxf(pmax, __shfl_xor(pmax, 32, 64));
    if (__any(pmax > mrun + 8.0f)) {
      float mn = fmaxf(mrun, pmax);
      float corr = __expf(mrun - mn);
      mrun = mn;
      lrun *= corr;
#pragma unroll
      for (int i = 0; i < 8; ++i) {
        O[i][0] *= corr; O[i][1] *= corr; O[i][2] *= corr; O[i][3] *= corr;
      }
    }
    float rsum = 0.f;
#pragma unroll
    for (int nt = 0; nt < 4; ++nt) {
      float p0 = __expf(s[nt][0] - mrun);
      float p1 = __expf(s[nt][1] - mrun);
      float p2 = __expf(s[nt][2] - mrun);
      float p3 = __expf(s[nt][3] - mrun);
      rsum += (p0 + p1) + (p2 + p3);
      uint2 d_;
      d_.x = cvt_pk2(p0, p1);
      d_.y = cvt_pk2(p2, p3);
      // PW write, swizzled: unit 2nt+(g>>1), 8B half g&1
      *(uint2*)(pwRow + 16 * ((2 * nt + (g >> 1)) ^ sx) + 8 * (g & 1)) = d_;
    }
    rsum += __shfl_xor(rsum, 16, 64);
    rsum += __shfl_xor(rsum, 32, 64);
    lrun += rsum;

    // ---- O^T += V^T P^T ----
    __builtin_amdgcn_s_setprio(1);
#pragma unroll
    for (int ks = 0; ks < 2; ++ks) {
      bf16x8 pfrag = *(const bf16x8*)(pwRow + foffA[ks]);
#pragma unroll
      for (int nt = 0; nt < 8; ++nt) {
        bf16x8 vfr = *(const bf16x8*)(VTp + (16 * nt + c) * 128 + foffA[ks]);
        O[nt] = __builtin_amdgcn_mfma_f32_16x16x32_bf16(vfr, pfrag, O[nt], 0, 0, 0);
      }
    }
    __builtin_amdgcn_s_setprio(0);
    __syncthreads();  // barrier B: all reads of tile t done
  }

  // ---- normalize + store ----
  float inv = 1.0f / lrun;
  float* ob = out + ((size_t)b * M_ + m0 + mrow) * H_;
#pragma unroll
  for (int nt = 0; nt < 8; ++nt) {
    float4 vv;
    vv.x = O[nt][0] * inv; vv.y = O[nt][1] * inv;
    vv.z = O[nt][2] * inv; vv.w = O[nt][3] * inv;
    *(float4*)(ob + 16 * nt + 4 * g) = vv;
  }
}

// ======================= fallback (round-2 kernel, no ws) =======================
#define PITCH_A  264
#define PITCH_VT 136
#define PITCH_PR 264
#define PITCH_PW 136
#define OFF_K  0
#define OFF_VT 16896
#define OFF_PT 34304
#define OFF_PR 51200
#define OFF_PW 68096
#define LDS_FB 76800

__global__ void __launch_bounds__(256, 2) seqattn_fb(
    const float* __restrict__ q, const float* __restrict__ kkey,
    const float* __restrict__ vval, const float* __restrict__ pe,
    float* __restrict__ out) {
  extern __shared__ char smem[];
  char* KL = smem + OFF_K;
  char* VT = smem + OFF_VT;
  char* PT = smem + OFF_PT;
  char* PR = smem + OFF_PR;
  char* PW = smem + OFF_PW;

  int jb = blockIdx.x;
  int o  = (jb & 7) * 64 + (jb >> 3);
  int b  = o >> 4;
  int m0 = (o & 15) * 64;

  int tid  = threadIdx.x;
  int w    = tid >> 6;
  int lane = tid & 63;
  int g    = lane >> 4;
  int c    = lane & 15;
  int r0   = tid >> 5;
  int c4   = tid & 31;

  const float* qbase = q    + ((size_t)b * M_  + m0) * H_;
  const float* kbase = kkey + ((size_t)b * KL_ + m0) * H_;
  const float* vbase = vval + ((size_t)b * KL_ + m0) * H_;

  float4 kpre[8];
  float  vpre[32];
  float  ppre[32];

#define LOADK(tt) do {                                                        \
    const float* kb_ = kbase + (size_t)(64 * (tt)) * H_;                      \
    _Pragma("unroll")                                                         \
    for (int p = 0; p < 8; ++p)                                               \
      kpre[p] = *(const float4*)(kb_ + (p * 8 + r0) * H_ + c4 * 4);           \
  } while (0)
#define WRITEK() do {                                                         \
    _Pragma("unroll")                                                         \
    for (int p = 0; p < 8; ++p) {                                             \
      float4 v_ = kpre[p];                                                    \
      uint2 d_; d_.x = cvt_pk2(v_.x, v_.y); d_.y = cvt_pk2(v_.z, v_.w);       \
      *(uint2*)(KL + (p * 8 + r0) * PITCH_A + c4 * 8) = d_;                   \
    }                                                                         \
  } while (0)
#define LOADV(tt) do {                                                        \
    const float* vb_ = vbase + (size_t)(64 * (tt)) * H_;                      \
    _Pragma("unroll")                                                         \
    for (int qq = 0; qq < 4; ++qq) {                                          \
      int kq_ = 4 * (4 * w + qq);                                             \
      _Pragma("unroll")                                                       \
      for (int r = 0; r < 4; ++r) {                                           \
        vpre[qq * 8 + r * 2 + 0] = vb_[(kq_ + r) * H_ + lane];                \
        vpre[qq * 8 + r * 2 + 1] = vb_[(kq_ + r) * H_ + lane + 64];           \
      }                                                                       \
    }                                                                         \
  } while (0)
#define WRITEV() do {                                                         \
    _Pragma("unroll")                                                         \
    for (int qq = 0; qq < 4; ++qq) {                                          \
      int kq_ = 4 * w + qq;                                                   \
      uint2 lo_, hi_;                                                         \
      lo_.x = cvt_pk2(vpre[qq * 8 + 0], vpre[qq * 8 + 2]);                    \
      lo_.y = cvt_pk2(vpre[qq * 8 + 4], vpre[qq * 8 + 6]);                    \
      hi_.x = cvt_pk2(vpre[qq * 8 + 1], vpre[qq * 8 + 3]);                    \
      hi_.y = cvt_pk2(vpre[qq * 8 + 5], vpre[qq * 8 + 7]);                    \
      *(uint2*)(VT + lane * PITCH_VT + 8 * kq_) = lo_;                        \
      *(uint2*)(VT + (lane + 64) * PITCH_VT + 8 * kq_) = hi_;                 \
    }                                                                         \
  } while (0)
#define LOADP(tt) do {                                                        \
    const float* pb_ = pe + 64 * (tt);                                        \
    _Pragma("unroll")                                                         \
    for (int qq = 0; qq < 8; ++qq) {                                          \
      int h_ = 4 * (8 * w + qq);                                              \
      _Pragma("unroll")                                                       \
      for (int r = 0; r < 4; ++r)                                             \
        ppre[qq * 4 + r] = pb_[(h_ + r) * SPAN_ + lane];                      \
    }                                                                         \
  } while (0)
#define WRITEP() do {                                                         \
    _Pragma("unroll")                                                         \
    for (int qq = 0; qq < 8; ++qq) {                                          \
      uint2 d_;                                                               \
      d_.x = cvt_pk2(ppre[qq * 4 + 0], ppre[qq * 4 + 1]);                     \
      d_.y = cvt_pk2(ppre[qq * 4 + 2], ppre[qq * 4 + 3]);                     \
      *(uint2*)(PT + lane * PITCH_A + 8 * (8 * w + qq)) = d_;                 \
    }                                                                         \
  } while (0)

  {
    float4 qpre[8];
#pragma unroll
    for (int p = 0; p < 8; ++p)
      qpre[p] = *(const float4*)(qbase + (p * 8 + r0) * H_ + c4 * 4);
    LOADK(0); LOADV(0); LOADP(0);
#pragma unroll
    for (int p = 0; p < 8; ++p) {
      float4 v_ = qpre[p];
      uint2 d_;
      d_.x = cvt_pk2(v_.x * SCALE, v_.y * SCALE);
      d_.y = cvt_pk2(v_.z * SCALE, v_.w * SCALE);
      *(uint2*)(PR + (p * 8 + r0) * PITCH_PR + c4 * 8) = d_;
    }
    WRITEK(); WRITEV(); WRITEP();
    LOADK(1); LOADV(1); LOADP(1);
  }
  __syncthreads();

  bf16x8 qf[4];
#pragma unroll
  for (int hs = 0; hs < 4; ++hs)
    qf[hs] = ldfrag(PR + (w * 16 + c) * PITCH_PR + hs * 64 + g * 16);

  f32x4 O[8];
#pragma unroll
  for (int i = 0; i < 8; ++i) { O[i][0] = 0.f; O[i][1] = 0.f; O[i][2] = 0.f; O[i][3] = 0.f; }
  float mrun = -1e30f, lrun = 0.f;
  const int mrow = 16 * w + c;
  char* prRow = PR + mrow * PITCH_PR;
  char* pwRow = PW + mrow * PITCH_PW;

#pragma unroll 1
  for (int t = 0; t < NITER; ++t) {
    if (t < 16) {
#pragma unroll
      for (int lt = 0; lt < 4; ++lt) {
        f32x4 pb = {0.f, 0.f, 0.f, 0.f};
#pragma unroll
        for (int hs = 0; hs < 4; ++hs)
          pb = __builtin_amdgcn_mfma_f32_16x16x32_bf16(
              ldfrag(PT + (16 * lt + c) * PITCH_A + hs * 64 + g * 16), qf[hs], pb, 0, 0, 0);
#pragma unroll
        for (int rr = 0; rr < 4; ++rr) {
          int x = (64 * t + 16 * lt + 4 * g + rr + mrow) & 127;
          *(unsigned short*)(prRow + x * 2) = f2b(pb[rr]);
        }
      }
    }
    f32x4 s[4];
#pragma unroll
    for (int nt = 0; nt < 4; ++nt) {
      f32x4 acc = {0.f, 0.f, 0.f, 0.f};
#pragma unroll
      for (int hs = 0; hs < 4; ++hs)
        acc = __builtin_amdgcn_mfma_f32_16x16x32_bf16(
            ldfrag(KL + (16 * nt + c) * PITCH_A + hs * 64 + g * 16), qf[hs], acc, 0, 0, 0);
      s[nt] = acc;
    }
#pragma unroll
    for (int nt = 0; nt < 4; ++nt) {
      int x = (64 * t + 16 * nt + 4 * g) & 127;
      ushort4 bv = *(const ushort4*)(prRow + x * 2);
      int lbase = 64 * t + 16 * nt + 4 * g - mrow;
      const unsigned short* bp = (const unsigned short*)&bv;
#pragma unroll
      for (int rr = 0; rr < 4; ++rr) {
        float sv = s[nt][rr] + b2f(bp[rr]);
        s[nt][rr] = ((unsigned)(lbase + rr) < 1024u) ? sv : -1e30f;
      }
    }
    float pmax = -1e30f;
#pragma unroll
    for (int nt = 0; nt < 4; ++nt)
#pragma unroll
      for (int rr = 0; rr < 4; ++rr) pmax = fmaxf(pmax, s[nt][rr]);
    pmax = fmaxf(pmax, __shfl_xor(pmax, 16, 64));
    pmax = fmaxf(pmax, __shfl_xor(pmax, 32, 64));
    if (__any(pmax > mrun + 8.0f)) {
      float mn = fmaxf(mrun, pmax);
      float corr = __expf(mrun - mn);
      mrun = mn;
      lrun *= corr;
#pragma unroll
      for (int i = 0; i < 8; ++i) {
        O[i][0] *= corr; O[i][1] *= corr; O[i][2] *= corr; O[i][3] *= corr;
      }
    }
    float rsum = 0.f;
#pragma unroll
    for (int nt = 0; nt < 4; ++nt) {
      float p0 = __expf(s[nt][0] - mrun);
      float p1 = __expf(s[nt][1] - mrun);
      float p2 = __expf(s[nt][2] - mrun);
      float p3 = __expf(s[nt][3] - mrun);
      rsum += (p0 + p1) + (p2 + p3);
      uint2 d_;
      d_.x = cvt_pk2(p0, p1);
      d_.y = cvt_pk2(p2, p3);
      *(uint2*)(pwRow + (16 * nt + 4 * g) * 2) = d_;
    }
    rsum += __shfl_xor(rsum, 16, 64);
    rsum += __shfl_xor(rsum, 32, 64);
    lrun += rsum;
#pragma unroll
    for (int ks = 0; ks < 2; ++ks) {
      bf16x8 pfrag = ldfrag(pwRow + ks * 64 + g * 16);
#pragma unroll
      for (int nt = 0; nt < 8; ++nt)
        O[nt] = __builtin_amdgcn_mfma_f32_16x16x32_bf16(
            ldfrag(VT + (16 * nt + c) * PITCH_VT + ks * 64 + g * 16), pfrag, O[nt], 0, 0, 0);
    }
    __syncthreads();
    if (t < 16) {
      WRITEK(); WRITEV();
      if (t < 15) {
        WRITEP();
        LOADK(t + 2); LOADV(t + 2);
        if (t + 2 < 16) LOADP(t + 2);
      }
    }
    __syncthreads();
  }

  float inv = 1.0f / lrun;
  float* ob = out + ((size_t)b * M_ + m0 + mrow) * H_;
#pragma unroll
  for (int nt = 0; nt < 8; ++nt) {
    float4 vv;
    vv.x = O[nt][0] * inv; vv.y = O[nt][1] * inv;
    vv.z = O[nt][2] * inv; vv.w = O[nt][3] * inv;
    *(float4*)(ob + 16 * nt + 4 * g) = vv;
  }
}
#undef LOADK
#undef WRITEK
#undef LOADV
#undef WRITEV
#undef LOADP
#undef WRITEP

extern "C" void kernel_launch(void* const* d_in, const int* in_sizes, int n_in,
                              void* d_out, int out_size, void* d_ws, size_t ws_size,
                              hipStream_t stream) {
  const float* q  = (const float*)d_in[0];
  const float* k  = (const float*)d_in[1];
  const float* v  = (const float*)d_in[2];
  const float* pe = (const float*)d_in[3];
  float* out = (float*)d_out;

  if (ws_size >= WSNEED) {
    char* ws = (char*)d_ws;
    convP2<<<dim3(16), dim3(256), 0, stream>>>(pe, ws);
    (void)hipFuncSetAttribute(reinterpret_cast<const void*>(seqattn_main),
                              hipFuncAttributeMaxDynamicSharedMemorySize, LDS_MAIN);
    seqattn_main<<<dim3(512), dim3(256), LDS_MAIN, stream>>>(q, k, v, ws, out);
  } else {
    (void)hipFuncSetAttribute(reinterpret_cast<const void*>(seqattn_fb),
                              hipFuncAttributeMaxDynamicSharedMemorySize, LDS_FB);
    seqattn_fb<<<dim3(512), dim3(256), LDS_FB, stream>>>(q, k, v, pe, out);
  }
}

// Round 8
// 80.414 us; speedup vs baseline: 1.4044x; 1.3110x over previous
//
#include <hip/hip_runtime.h>
#include <hip/hip_bf16.h>

// Problem constants
#define B_    32
#define M_    1024
#define H_    128
#define SPAN_ 1024
#define KL_   2048
#define NITER 17
#define SCALE 0.08838834764831845f

typedef __attribute__((ext_vector_type(8))) short bf16x8;
typedef __attribute__((ext_vector_type(4))) float f32x4;

// workspace: pos bf16, 16 tiles of [64 l-rows][128 h] (256 B rows, linear)
#define WSNEED 262144ull

static __device__ __forceinline__ unsigned int cvt_pk2(float lo, float hi) {
  unsigned int r;
  asm("v_cvt_pk_bf16_f32 %0, %1, %2" : "=v"(r) : "v"(lo), "v"(hi));
  return r;
}
static __device__ __forceinline__ unsigned short f2b(float x) {
  unsigned int u = __builtin_bit_cast(unsigned int, x);
  return (unsigned short)((u + 0x7FFFu + ((u >> 16) & 1u)) >> 16);
}
static __device__ __forceinline__ float b2f(unsigned short u) {
  return __builtin_bit_cast(float, ((unsigned int)u) << 16);
}
static __device__ __forceinline__ bf16x8 ldfrag(const char* p) {
  short4 a = *(const short4*)p;
  short4 b = *(const short4*)(p + 8);
  bf16x8 r;
  r[0] = a.x; r[1] = a.y; r[2] = a.z; r[3] = a.w;
  r[4] = b.x; r[5] = b.y; r[6] = b.z; r[7] = b.w;
  return r;
}

// ======================= pos pre-conversion (tiny, ~1-2us) =======================
__global__ void __launch_bounds__(256) convP2(const float* __restrict__ pe,
                                              char* __restrict__ out) {
  __shared__ float tile[128 * 66];
  int lt = blockIdx.x, tid = threadIdx.x;
#pragma unroll
  for (int i = 0; i < 8; ++i) {
    int idx = i * 256 + tid;
    int h = idx >> 4, c4 = idx & 15;
    float4 x = *(const float4*)(pe + (size_t)h * 1024 + lt * 64 + c4 * 4);
    tile[h * 66 + c4 * 4 + 0] = x.x; tile[h * 66 + c4 * 4 + 1] = x.y;
    tile[h * 66 + c4 * 4 + 2] = x.z; tile[h * 66 + c4 * 4 + 3] = x.w;
  }
  __syncthreads();
  char* dst = out + (size_t)lt * 16384;
#pragma unroll
  for (int j = 0; j < 4; ++j) {
    int u = tid >> 4;               // 0..15  (h-chunk of 8)
    int l = (tid & 15) + 16 * j;    // 0..63
    uint4 d;
    d.x = cvt_pk2(tile[(8 * u + 0) * 66 + l], tile[(8 * u + 1) * 66 + l]);
    d.y = cvt_pk2(tile[(8 * u + 2) * 66 + l], tile[(8 * u + 3) * 66 + l]);
    d.z = cvt_pk2(tile[(8 * u + 4) * 66 + l], tile[(8 * u + 5) * 66 + l]);
    d.w = cvt_pk2(tile[(8 * u + 6) * 66 + l], tile[(8 * u + 7) * 66 + l]);
    *(uint4*)(dst + l * 256 + 16 * u) = d;
  }
}

// ======================= main kernel (round-2 structure + pos-ws + setprio) ====
#define PITCH_A  264
#define PITCH_VT 136
#define PITCH_PR 264
#define PITCH_PW 136
#define OFF_K  0
#define OFF_VT 16896
#define OFF_PT 34304
#define OFF_PR 51200
#define OFF_PW 68096
#define LDS_FB 76800

__global__ void __launch_bounds__(256, 2) seqattn_main(
    const float* __restrict__ q, const float* __restrict__ kkey,
    const float* __restrict__ vval, const char* __restrict__ posws,
    float* __restrict__ out) {
  extern __shared__ char smem[];
  char* KL = smem + OFF_K;
  char* VT = smem + OFF_VT;
  char* PT = smem + OFF_PT;
  char* PR = smem + OFF_PR;
  char* PW = smem + OFF_PW;

  int jb = blockIdx.x;
  int o  = (jb & 7) * 64 + (jb >> 3);
  int b  = o >> 4;
  int m0 = (o & 15) * 64;

  int tid  = threadIdx.x;
  int w    = tid >> 6;
  int lane = tid & 63;
  int g    = lane >> 4;
  int c    = lane & 15;
  int r0   = tid >> 5;
  int c4   = tid & 31;

  const float* qbase = q    + ((size_t)b * M_  + m0) * H_;
  const float* kbase = kkey + ((size_t)b * KL_ + m0) * H_;
  const float* vbase = vval + ((size_t)b * KL_ + m0) * H_;

  float4 kpre[8];
  float  vpre[32];
  uint4  ppre[4];

#define LOADK(tt) do {                                                        \
    const float* kb_ = kbase + (size_t)(64 * (tt)) * H_;                      \
    _Pragma("unroll")                                                         \
    for (int p = 0; p < 8; ++p)                                               \
      kpre[p] = *(const float4*)(kb_ + (p * 8 + r0) * H_ + c4 * 4);           \
  } while (0)
#define WRITEK() do {                                                         \
    _Pragma("unroll")                                                         \
    for (int p = 0; p < 8; ++p) {                                             \
      float4 v_ = kpre[p];                                                    \
      uint2 d_; d_.x = cvt_pk2(v_.x, v_.y); d_.y = cvt_pk2(v_.z, v_.w);       \
      *(uint2*)(KL + (p * 8 + r0) * PITCH_A + c4 * 8) = d_;                   \
    }                                                                         \
  } while (0)
#define LOADV(tt) do {                                                        \
    const float* vb_ = vbase + (size_t)(64 * (tt)) * H_;                      \
    _Pragma("unroll")                                                         \
    for (int qq = 0; qq < 4; ++qq) {                                          \
      int kq_ = 4 * (4 * w + qq);                                             \
      _Pragma("unroll")                                                       \
      for (int r = 0; r < 4; ++r) {                                           \
        vpre[qq * 8 + r * 2 + 0] = vb_[(kq_ + r) * H_ + lane];                \
        vpre[qq * 8 + r * 2 + 1] = vb_[(kq_ + r) * H_ + lane + 64];           \
      }                                                                       \
    }                                                                         \
  } while (0)
#define WRITEV() do {                                                         \
    _Pragma("unroll")                                                         \
    for (int qq = 0; qq < 4; ++qq) {                                          \
      int kq_ = 4 * w + qq;                                                   \
      uint2 lo_, hi_;                                                         \
      lo_.x = cvt_pk2(vpre[qq * 8 + 0], vpre[qq * 8 + 2]);                    \
      lo_.y = cvt_pk2(vpre[qq * 8 + 4], vpre[qq * 8 + 6]);                    \
      hi_.x = cvt_pk2(vpre[qq * 8 + 1], vpre[qq * 8 + 3]);                    \
      hi_.y = cvt_pk2(vpre[qq * 8 + 5], vpre[qq * 8 + 7]);                    \
      *(uint2*)(VT + lane * PITCH_VT + 8 * kq_) = lo_;                        \
      *(uint2*)(VT + (lane + 64) * PITCH_VT + 8 * kq_) = hi_;                 \
    }                                                                         \
  } while (0)
#define LOADP2(tt) do {                                                       \
    const char* pt_ = posws + (size_t)(tt) * 16384;                           \
    _Pragma("unroll")                                                         \
    for (int i = 0; i < 4; ++i)                                               \
      ppre[i] = *(const uint4*)(pt_ + (i * 256 + tid) * 16);                  \
  } while (0)
#define WRITEP2() do {                                                        \
    _Pragma("unroll")                                                         \
    for (int i = 0; i < 4; ++i) {                                             \
      int idx_ = i * 256 + tid;                                               \
      int pr_ = idx_ >> 4, pu_ = idx_ & 15;                                   \
      uint2 lo_, hi_;                                                         \
      lo_.x = ppre[i].x; lo_.y = ppre[i].y;                                   \
      hi_.x = ppre[i].z; hi_.y = ppre[i].w;                                   \
      *(uint2*)(PT + pr_ * PITCH_A + pu_ * 16) = lo_;                         \
      *(uint2*)(PT + pr_ * PITCH_A + pu_ * 16 + 8) = hi_;                     \
    }                                                                         \
  } while (0)

  // ---- prologue: Q -> PR (pre-scaled), tile 0, then issue tile 1 ----
  {
    float4 qpre[8];
#pragma unroll
    for (int p = 0; p < 8; ++p)
      qpre[p] = *(const float4*)(qbase + (p * 8 + r0) * H_ + c4 * 4);
    LOADK(0); LOADV(0); LOADP2(0);
#pragma unroll
    for (int p = 0; p < 8; ++p) {
      float4 v_ = qpre[p];
      uint2 d_;
      d_.x = cvt_pk2(v_.x * SCALE, v_.y * SCALE);
      d_.y = cvt_pk2(v_.z * SCALE, v_.w * SCALE);
      *(uint2*)(PR + (p * 8 + r0) * PITCH_PR + c4 * 8) = d_;
    }
    WRITEK(); WRITEV(); WRITEP2();
    LOADK(1); LOADV(1); LOADP2(1);
  }
  __syncthreads();

  bf16x8 qf[4];
#pragma unroll
  for (int hs = 0; hs < 4; ++hs)
    qf[hs] = ldfrag(PR + (w * 16 + c) * PITCH_PR + hs * 64 + g * 16);

  f32x4 O[8];
#pragma unroll
  for (int i = 0; i < 8; ++i) { O[i][0] = 0.f; O[i][1] = 0.f; O[i][2] = 0.f; O[i][3] = 0.f; }
  float mrun = -1e30f, lrun = 0.f;
  const int mrow = 16 * w + c;
  char* prRow = PR + mrow * PITCH_PR;
  char* pwRow = PW + mrow * PITCH_PW;

#pragma unroll 1
  for (int t = 0; t < NITER; ++t) {
    // ---- bias chunk: ring[j&127] = q[mrow] . pos[:, l] ----
    if (t < 16) {
      __builtin_amdgcn_s_setprio(1);
#pragma unroll
      for (int lt = 0; lt < 4; ++lt) {
        f32x4 pb = {0.f, 0.f, 0.f, 0.f};
#pragma unroll
        for (int hs = 0; hs < 4; ++hs)
          pb = __builtin_amdgcn_mfma_f32_16x16x32_bf16(
              ldfrag(PT + (16 * lt + c) * PITCH_A + hs * 64 + g * 16), qf[hs], pb, 0, 0, 0);
#pragma unroll
        for (int rr = 0; rr < 4; ++rr) {
          int x = (64 * t + 16 * lt + 4 * g + rr + mrow) & 127;
          *(unsigned short*)(prRow + x * 2) = f2b(pb[rr]);
        }
      }
      __builtin_amdgcn_s_setprio(0);
    }
    // ---- S^T = K Q^T ----
    f32x4 s[4];
    __builtin_amdgcn_s_setprio(1);
#pragma unroll
    for (int nt = 0; nt < 4; ++nt) {
      f32x4 acc = {0.f, 0.f, 0.f, 0.f};
#pragma unroll
      for (int hs = 0; hs < 4; ++hs)
        acc = __builtin_amdgcn_mfma_f32_16x16x32_bf16(
            ldfrag(KL + (16 * nt + c) * PITCH_A + hs * 64 + g * 16), qf[hs], acc, 0, 0, 0);
      s[nt] = acc;
    }
    __builtin_amdgcn_s_setprio(0);
    // ---- bias add (j-indexed ring, 8B reads) + band mask ----
#pragma unroll
    for (int nt = 0; nt < 4; ++nt) {
      int x = (64 * t + 16 * nt + 4 * g) & 127;
      ushort4 bv = *(const ushort4*)(prRow + x * 2);
      int lbase = 64 * t + 16 * nt + 4 * g - mrow;
      const unsigned short* bp = (const unsigned short*)&bv;
#pragma unroll
      for (int rr = 0; rr < 4; ++rr) {
        float sv = s[nt][rr] + b2f(bp[rr]);
        s[nt][rr] = ((unsigned)(lbase + rr) < 1024u) ? sv : -1e30f;
      }
    }
    // ---- online softmax (per-lane row, defer-max) ----
    float pmax = -1e30f;
#pragma unroll
    for (int nt = 0; nt < 4; ++nt)
#pragma unroll
      for (int rr = 0; rr < 4; ++rr) pmax = fmaxf(pmax, s[nt][rr]);
    pmax = fmaxf(pmax, __shfl_xor(pmax, 16, 64));
    pmax = fmaxf(pmax, __shfl_xor(pmax, 32, 64));
    if (__any(pmax > mrun + 8.0f)) {
      float mn = fmaxf(mrun, pmax);
      float corr = __expf(mrun - mn);
      mrun = mn;
      lrun *= corr;
#pragma unroll
      for (int i = 0; i < 8; ++i) {
        O[i][0] *= corr; O[i][1] *= corr; O[i][2] *= corr; O[i][3] *= corr;
      }
    }
    float rsum = 0.f;
#pragma unroll
    for (int nt = 0; nt < 4; ++nt) {
      float p0 = __expf(s[nt][0] - mrun);
      float p1 = __expf(s[nt][1] - mrun);
      float p2 = __expf(s[nt][2] - mrun);
      float p3 = __expf(s[nt][3] - mrun);
      rsum += (p0 + p1) + (p2 + p3);
      uint2 d_;
      d_.x = cvt_pk2(p0, p1);
      d_.y = cvt_pk2(p2, p3);
      *(uint2*)(pwRow + (16 * nt + 4 * g) * 2) = d_;
    }
    rsum += __shfl_xor(rsum, 16, 64);
    rsum += __shfl_xor(rsum, 32, 64);
    lrun += rsum;
    // ---- O^T += V^T P^T ----
    __builtin_amdgcn_s_setprio(1);
#pragma unroll
    for (int ks = 0; ks < 2; ++ks) {
      bf16x8 pfrag = ldfrag(pwRow + ks * 64 + g * 16);
#pragma unroll
      for (int nt = 0; nt < 8; ++nt)
        O[nt] = __builtin_amdgcn_mfma_f32_16x16x32_bf16(
            ldfrag(VT + (16 * nt + c) * PITCH_VT + ks * 64 + g * 16), pfrag, O[nt], 0, 0, 0);
    }
    __builtin_amdgcn_s_setprio(0);
    __syncthreads();
    if (t < 16) {
      WRITEK(); WRITEV();
      if (t < 15) {
        WRITEP2();
        LOADK(t + 2); LOADV(t + 2);
        if (t + 2 < 16) LOADP2(t + 2);
      }
    }
    __syncthreads();
  }

  float inv = 1.0f / lrun;
  float* ob = out + ((size_t)b * M_ + m0 + mrow) * H_;
#pragma unroll
  for (int nt = 0; nt < 8; ++nt) {
    float4 vv;
    vv.x = O[nt][0] * inv; vv.y = O[nt][1] * inv;
    vv.z = O[nt][2] * inv; vv.w = O[nt][3] * inv;
    *(float4*)(ob + 16 * nt + 4 * g) = vv;
  }
}
#undef LOADK
#undef WRITEK
#undef LOADV
#undef WRITEV
#undef LOADP2
#undef WRITEP2

// ======================= fallback (round-2 kernel verbatim, no ws) ==========
__global__ void __launch_bounds__(256, 2) seqattn_fb(
    const float* __restrict__ q, const float* __restrict__ kkey,
    const float* __restrict__ vval, const float* __restrict__ pe,
    float* __restrict__ out) {
  extern __shared__ char smem[];
  char* KL = smem + OFF_K;
  char* VT = smem + OFF_VT;
  char* PT = smem + OFF_PT;
  char* PR = smem + OFF_PR;
  char* PW = smem + OFF_PW;

  int jb = blockIdx.x;
  int o  = (jb & 7) * 64 + (jb >> 3);
  int b  = o >> 4;
  int m0 = (o & 15) * 64;

  int tid  = threadIdx.x;
  int w    = tid >> 6;
  int lane = tid & 63;
  int g    = lane >> 4;
  int c    = lane & 15;
  int r0   = tid >> 5;
  int c4   = tid & 31;

  const float* qbase = q    + ((size_t)b * M_  + m0) * H_;
  const float* kbase = kkey + ((size_t)b * KL_ + m0) * H_;
  const float* vbase = vval + ((size_t)b * KL_ + m0) * H_;

  float4 kpre[8];
  float  vpre[32];
  float  ppre[32];

#define LOADK(tt) do {                                                        \
    const float* kb_ = kbase + (size_t)(64 * (tt)) * H_;                      \
    _Pragma("unroll")                                                         \
    for (int p = 0; p < 8; ++p)                                               \
      kpre[p] = *(const float4*)(kb_ + (p * 8 + r0) * H_ + c4 * 4);           \
  } while (0)
#define WRITEK() do {                                                         \
    _Pragma("unroll")                                                         \
    for (int p = 0; p < 8; ++p) {                                             \
      float4 v_ = kpre[p];                                                    \
      uint2 d_; d_.x = cvt_pk2(v_.x, v_.y); d_.y = cvt_pk2(v_.z, v_.w);       \
      *(uint2*)(KL + (p * 8 + r0) * PITCH_A + c4 * 8) = d_;                   \
    }                                                                         \
  } while (0)
#define LOADV(tt) do {                                                        \
    const float* vb_ = vbase + (size_t)(64 * (tt)) * H_;                      \
    _Pragma("unroll")                                                         \
    for (int qq = 0; qq < 4; ++qq) {                                          \
      int kq_ = 4 * (4 * w + qq);                                             \
      _Pragma("unroll")                                                       \
      for (int r = 0; r < 4; ++r) {                                           \
        vpre[qq * 8 + r * 2 + 0] = vb_[(kq_ + r) * H_ + lane];                \
        vpre[qq * 8 + r * 2 + 1] = vb_[(kq_ + r) * H_ + lane + 64];           \
      }                                                                       \
    }                                                                         \
  } while (0)
#define WRITEV() do {                                                         \
    _Pragma("unroll")                                                         \
    for (int qq = 0; qq < 4; ++qq) {                                          \
      int kq_ = 4 * w + qq;                                                   \
      uint2 lo_, hi_;                                                         \
      lo_.x = cvt_pk2(vpre[qq * 8 + 0], vpre[qq * 8 + 2]);                    \
      lo_.y = cvt_pk2(vpre[qq * 8 + 4], vpre[qq * 8 + 6]);                    \
      hi_.x = cvt_pk2(vpre[qq * 8 + 1], vpre[qq * 8 + 3]);                    \
      hi_.y = cvt_pk2(vpre[qq * 8 + 5], vpre[qq * 8 + 7]);                    \
      *(uint2*)(VT + lane * PITCH_VT + 8 * kq_) = lo_;                        \
      *(uint2*)(VT + (lane + 64) * PITCH_VT + 8 * kq_) = hi_;                 \
    }                                                                         \
  } while (0)
#define LOADP(tt) do {                                                        \
    const float* pb_ = pe + 64 * (tt);                                        \
    _Pragma("unroll")                                                         \
    for (int qq = 0; qq < 8; ++qq) {                                          \
      int h_ = 4 * (8 * w + qq);                                              \
      _Pragma("unroll")                                                       \
      for (int r = 0; r < 4; ++r)                                             \
        ppre[qq * 4 + r] = pb_[(h_ + r) * SPAN_ + lane];                      \
    }                                                                         \
  } while (0)
#define WRITEP() do {                                                         \
    _Pragma("unroll")                                                         \
    for (int qq = 0; qq < 8; ++qq) {                                          \
      uint2 d_;                                                               \
      d_.x = cvt_pk2(ppre[qq * 4 + 0], ppre[qq * 4 + 1]);                     \
      d_.y = cvt_pk2(ppre[qq * 4 + 2], ppre[qq * 4 + 3]);                     \
      *(uint2*)(PT + lane * PITCH_A + 8 * (8 * w + qq)) = d_;                 \
    }                                                                         \
  } while (0)

  {
    float4 qpre[8];
#pragma unroll
    for (int p = 0; p < 8; ++p)
      qpre[p] = *(const float4*)(qbase + (p * 8 + r0) * H_ + c4 * 4);
    LOADK(0); LOADV(0); LOADP(0);
#pragma unroll
    for (int p = 0; p < 8; ++p) {
      float4 v_ = qpre[p];
      uint2 d_;
      d_.x = cvt_pk2(v_.x * SCALE, v_.y * SCALE);
      d_.y = cvt_pk2(v_.z * SCALE, v_.w * SCALE);
      *(uint2*)(PR + (p * 8 + r0) * PITCH_PR + c4 * 8) = d_;
    }
    WRITEK(); WRITEV(); WRITEP();
    LOADK(1); LOADV(1); LOADP(1);
  }
  __syncthreads();

  bf16x8 qf[4];
#pragma unroll
  for (int hs = 0; hs < 4; ++hs)
    qf[hs] = ldfrag(PR + (w * 16 + c) * PITCH_PR + hs * 64 + g * 16);

  f32x4 O[8];
#pragma unroll
  for (int i = 0; i < 8; ++i) { O[i][0] = 0.f; O[i][1] = 0.f; O[i][2] = 0.f; O[i][3] = 0.f; }
  float mrun = -1e30f, lrun = 0.f;
  const int mrow = 16 * w + c;
  char* prRow = PR + mrow * PITCH_PR;
  char* pwRow = PW + mrow * PITCH_PW;

#pragma unroll 1
  for (int t = 0; t < NITER; ++t) {
    if (t < 16) {
#pragma unroll
      for (int lt = 0; lt < 4; ++lt) {
        f32x4 pb = {0.f, 0.f, 0.f, 0.f};
#pragma unroll
        for (int hs = 0; hs < 4; ++hs)
          pb = __builtin_amdgcn_mfma_f32_16x16x32_bf16(
              ldfrag(PT + (16 * lt + c) * PITCH_A + hs * 64 + g * 16), qf[hs], pb, 0, 0, 0);
#pragma unroll
        for (int rr = 0; rr < 4; ++rr) {
          int x = (64 * t + 16 * lt + 4 * g + rr + mrow) & 127;
          *(unsigned short*)(prRow + x * 2) = f2b(pb[rr]);
        }
      }
    }
    f32x4 s[4];
#pragma unroll
    for (int nt = 0; nt < 4; ++nt) {
      f32x4 acc = {0.f, 0.f, 0.f, 0.f};
#pragma unroll
      for (int hs = 0; hs < 4; ++hs)
        acc = __builtin_amdgcn_mfma_f32_16x16x32_bf16(
            ldfrag(KL + (16 * nt + c) * PITCH_A + hs * 64 + g * 16), qf[hs], acc, 0, 0, 0);
      s[nt] = acc;
    }
#pragma unroll
    for (int nt = 0; nt < 4; ++nt) {
      int x = (64 * t + 16 * nt + 4 * g) & 127;
      ushort4 bv = *(const ushort4*)(prRow + x * 2);
      int lbase = 64 * t + 16 * nt + 4 * g - mrow;
      const unsigned short* bp = (const unsigned short*)&bv;
#pragma unroll
      for (int rr = 0; rr < 4; ++rr) {
        float sv = s[nt][rr] + b2f(bp[rr]);
        s[nt][rr] = ((unsigned)(lbase + rr) < 1024u) ? sv : -1e30f;
      }
    }
    float pmax = -1e30f;
#pragma unroll
    for (int nt = 0; nt < 4; ++nt)
#pragma unroll
      for (int rr = 0; rr < 4; ++rr) pmax = fmaxf(pmax, s[nt][rr]);
    pmax = fmaxf(pmax, __shfl_xor(pmax, 16, 64));
    pmax = fmaxf(pmax, __shfl_xor(pmax, 32, 64));
    if (__any(pmax > mrun + 8.0f)) {
      float mn = fmaxf(mrun, pmax);
      float corr = __expf(mrun - mn);
      mrun = mn;
      lrun *= corr;
#pragma unroll
      for (int i = 0; i < 8; ++i) {
        O[i][0] *= corr; O[i][1] *= corr; O[i][2] *= corr; O[i][3] *= corr;
      }
    }
    float rsum = 0.f;
#pragma unroll
    for (int nt = 0; nt < 4; ++nt) {
      float p0 = __expf(s[nt][0] - mrun);
      float p1 = __expf(s[nt][1] - mrun);
      float p2 = __expf(s[nt][2] - mrun);
      float p3 = __expf(s[nt][3] - mrun);
      rsum += (p0 + p1) + (p2 + p3);
      uint2 d_;
      d_.x = cvt_pk2(p0, p1);
      d_.y = cvt_pk2(p2, p3);
      *(uint2*)(pwRow + (16 * nt + 4 * g) * 2) = d_;
    }
    rsum += __shfl_xor(rsum, 16, 64);
    rsum += __shfl_xor(rsum, 32, 64);
    lrun += rsum;
#pragma unroll
    for (int ks = 0; ks < 2; ++ks) {
      bf16x8 pfrag = ldfrag(pwRow + ks * 64 + g * 16);
#pragma unroll
      for (int nt = 0; nt < 8; ++nt)
        O[nt] = __builtin_amdgcn_mfma_f32_16x16x32_bf16(
            ldfrag(VT + (16 * nt + c) * PITCH_VT + ks * 64 + g * 16), pfrag, O[nt], 0, 0, 0);
    }
    __syncthreads();
    if (t < 16) {
      WRITEK(); WRITEV();
      if (t < 15) {
        WRITEP();
        LOADK(t + 2); LOADV(t + 2);
        if (t + 2 < 16) LOADP(t + 2);
      }
    }
    __syncthreads();
  }

  float inv = 1.0f / lrun;
  float* ob = out + ((size_t)b * M_ + m0 + mrow) * H_;
#pragma unroll
  for (int nt = 0; nt < 8; ++nt) {
    float4 vv;
    vv.x = O[nt][0] * inv; vv.y = O[nt][1] * inv;
    vv.z = O[nt][2] * inv; vv.w = O[nt][3] * inv;
    *(float4*)(ob + 16 * nt + 4 * g) = vv;
  }
}
#undef LOADK
#undef WRITEK
#undef LOADV
#undef WRITEV
#undef LOADP
#undef WRITEP

extern "C" void kernel_launch(void* const* d_in, const int* in_sizes, int n_in,
                              void* d_out, int out_size, void* d_ws, size_t ws_size,
                              hipStream_t stream) {
  const float* q  = (const float*)d_in[0];
  const float* k  = (const float*)d_in[1];
  const float* v  = (const float*)d_in[2];
  const float* pe = (const float*)d_in[3];
  float* out = (float*)d_out;

  if (ws_size >= WSNEED) {
    char* ws = (char*)d_ws;
    convP2<<<dim3(16), dim3(256), 0, stream>>>(pe, ws);
    (void)hipFuncSetAttribute(reinterpret_cast<const void*>(seqattn_main),
                              hipFuncAttributeMaxDynamicSharedMemorySize, LDS_FB);
    seqattn_main<<<dim3(512), dim3(256), LDS_FB, stream>>>(q, k, v, ws, out);
  } else {
    (void)hipFuncSetAttribute(reinterpret_cast<const void*>(seqattn_fb),
                              hipFuncAttributeMaxDynamicSharedMemorySize, LDS_FB);
    seqattn_fb<<<dim3(512), dim3(256), LDS_FB, stream>>>(q, k, v, pe, out);
  }
}